// Round 4
// baseline (173.651 us; speedup 1.0000x reference)
//
#include <hip/hip_runtime.h>

// RegL1Loss: out[b] = sum_{p,d} valid * |preds[b, idx[b,p,d]] - val| / num_people[b]
// B=32, P=64, D=34, L=1048576. gts layout [B,P,D,3] = (val, idx, flag).
//
// Timed region is dominated by ~158us of harness d_ws poison (2x79us fills at
// ~86% HBM peak — fixed). Controllable share: one latency-bound dispatch.
// Structure (best measured, R2) + last-block finalize to kill the 2nd launch:
//   grid (16,32) x 256: one wave per person (lane=dim, 34 active), depth-1
//   gather chains. Block reduces 4 persons in LDS, atomicAdds fp32 partials
//   (sum, valid-person count) per image into d_ws, bumps a device counter;
//   block #512 divides and writes d_out. d_ws accumulators zeroed by a tiny
//   hipMemsetAsync (graph-capturable).

#define B_ 32
#define P_ 64
#define D_ 34
#define L_ 1048576
#define GPB 4                      // persons (waves) per block
#define BLK_PER_IMG (P_ / GPB)     // 16
#define NBLOCKS (B_ * BLK_PER_IMG) // 512

__global__ __launch_bounds__(256) void reg_l1_onepass(
    const float* __restrict__ preds,
    const float* __restrict__ gts,
    float* __restrict__ ws,        // [0..31] sums, [32..63] counts, [64] counter
    float* __restrict__ out) {
  const int g    = blockIdx.x;            // person-group 0..15
  const int b    = blockIdx.y;            // image 0..31
  const int wave = threadIdx.x >> 6;      // 0..3
  const int lane = threadIdx.x & 63;
  const int p    = g * GPB + wave;        // person 0..63

  float contrib = 0.0f;
  int valid = 0;
  if (lane < D_) {
    const float* gt = gts + (((size_t)b * P_ + p) * D_ + lane) * 3;
    const float v    = gt[0];
    const float fidx = gt[1];
    const float flag = gt[2];
    if (flag > 0.0f) {
      contrib = fabsf(preds[(size_t)b * L_ + (int)fidx] - v);
      valid = 1;
    }
  }

  for (int off = 1; off < 64; off <<= 1) contrib += __shfl_xor(contrib, off);
  const unsigned long long bal = __ballot(valid);
  const float pcnt = (bal != 0ull) ? 1.0f : 0.0f;

  __shared__ float s_sum[GPB];
  __shared__ float s_cnt[GPB];
  __shared__ int   s_last;
  if (lane == 0) {
    s_sum[wave] = contrib;
    s_cnt[wave] = pcnt;
  }
  __syncthreads();

  if (threadIdx.x == 0) {
    const float ts = s_sum[0] + s_sum[1] + s_sum[2] + s_sum[3];
    const float tc = s_cnt[0] + s_cnt[1] + s_cnt[2] + s_cnt[3];
    atomicAdd(&ws[b], ts);
    atomicAdd(&ws[B_ + b], tc);
    __threadfence();   // make partials visible device-wide before the ticket
    const int old = atomicAdd((int*)&ws[2 * B_], 1);
    s_last = (old == NBLOCKS - 1) ? 1 : 0;
  }
  __syncthreads();

  if (s_last && threadIdx.x < B_) {
    const int i = threadIdx.x;
    const float s = __hip_atomic_load(&ws[i],      __ATOMIC_ACQUIRE, __HIP_MEMORY_SCOPE_AGENT);
    const float c = __hip_atomic_load(&ws[B_ + i], __ATOMIC_ACQUIRE, __HIP_MEMORY_SCOPE_AGENT);
    out[i] = s / c;   // >=1 valid person per image guaranteed by setup
  }
}

extern "C" void kernel_launch(void* const* d_in, const int* in_sizes, int n_in,
                              void* d_out, int out_size, void* d_ws, size_t ws_size,
                              hipStream_t stream) {
  const float* preds = (const float*)d_in[0];  // [B, L]
  const float* gts   = (const float*)d_in[1];  // [B, P, D, 3]
  float* out = (float*)d_out;                  // [B]
  float* ws  = (float*)d_ws;                   // 65 floats used

  hipMemsetAsync(ws, 0, (2 * B_ + 1) * sizeof(float), stream);
  dim3 grid(BLK_PER_IMG, B_);
  reg_l1_onepass<<<grid, 256, 0, stream>>>(preds, gts, ws, out);
}

// Round 5
// 164.300 us; speedup vs baseline: 1.0569x; 1.0569x over previous
//
#include <hip/hip_runtime.h>

// RegL1Loss: out[b] = sum_{p,d} valid * |preds[b, idx[b,p,d]] - val| / num_people[b]
// B=32, P=64, D=34, L=1048576. gts layout [B,P,D,3] = (val, idx, flag).
//
// REVERT to R2 (best measured: 164.0 us). R4's memset+atomic single-pass
// regressed (+4us tail serialization beyond fill noise). Timed region floor =
// two ~79us harness d_ws poison fills at ~85% HBM peak (fixed) + ~6us of our
// latency-bound dispatches.
//   Kernel 1: grid (16,32) x 256. One wave per person (lane = dim, 34 active
//             lanes) -> depth-1 gather chains. Block reduces 4 persons in LDS,
//             writes (sum, cnt) partials to deterministic d_ws slots.
//   Kernel 2: 32 blocks x 64 threads. Reduce 16 partials per image, divide.

#define B_ 32
#define P_ 64
#define D_ 34
#define L_ 1048576
#define GPB 4                      // persons (waves) per block
#define BLK_PER_IMG (P_ / GPB)     // 16

__global__ __launch_bounds__(256) void reg_l1_main(
    const float* __restrict__ preds,
    const float* __restrict__ gts,
    float* __restrict__ ws) {
  const int g    = blockIdx.x;            // person-group 0..15
  const int b    = blockIdx.y;            // image 0..31
  const int wave = threadIdx.x >> 6;      // 0..3
  const int lane = threadIdx.x & 63;
  const int p    = g * GPB + wave;        // person 0..63

  float contrib = 0.0f;
  int valid = 0;
  if (lane < D_) {
    const float* gt = gts + (((size_t)b * P_ + p) * D_ + lane) * 3;
    const float v    = gt[0];
    const float fidx = gt[1];
    const float flag = gt[2];
    if (flag > 0.0f) {
      const int idx = (int)fidx;          // exact: randint < 2^24
      contrib = fabsf(preds[(size_t)b * L_ + idx] - v);
      valid = 1;
    }
  }

  // Wave reduction: sum of contributions, any-valid via ballot.
  for (int off = 1; off < 64; off <<= 1) contrib += __shfl_xor(contrib, off);
  const unsigned long long bal = __ballot(valid);
  const float pcnt = (bal != 0ull) ? 1.0f : 0.0f;

  __shared__ float s_sum[GPB];
  __shared__ float s_cnt[GPB];
  if (lane == 0) {
    s_sum[wave] = contrib;
    s_cnt[wave] = pcnt;
  }
  __syncthreads();
  if (threadIdx.x == 0) {
    const float ts = s_sum[0] + s_sum[1] + s_sum[2] + s_sum[3];
    const float tc = s_cnt[0] + s_cnt[1] + s_cnt[2] + s_cnt[3];
    ws[b * BLK_PER_IMG + g] = ts;                        // partial sums
    ws[B_ * BLK_PER_IMG + b * BLK_PER_IMG + g] = tc;     // partial counts
  }
}

__global__ __launch_bounds__(64) void reg_l1_final(
    const float* __restrict__ ws,
    float* __restrict__ out) {
  const int b    = blockIdx.x;
  const int lane = threadIdx.x;   // 0..63
  float s = 0.0f, c = 0.0f;
  if (lane < BLK_PER_IMG) {
    s = ws[b * BLK_PER_IMG + lane];
    c = ws[B_ * BLK_PER_IMG + b * BLK_PER_IMG + lane];
  }
  for (int off = 1; off < BLK_PER_IMG; off <<= 1) {
    s += __shfl_xor(s, off);
    c += __shfl_xor(c, off);
  }
  if (lane == 0) out[b] = s / c;   // >=1 valid person guaranteed by setup
}

extern "C" void kernel_launch(void* const* d_in, const int* in_sizes, int n_in,
                              void* d_out, int out_size, void* d_ws, size_t ws_size,
                              hipStream_t stream) {
  const float* preds = (const float*)d_in[0];  // [B, L]
  const float* gts   = (const float*)d_in[1];  // [B, P, D, 3]
  float* out = (float*)d_out;                  // [B]
  float* ws  = (float*)d_ws;                   // 1024 floats used

  dim3 grid(BLK_PER_IMG, B_);
  reg_l1_main<<<grid, 256, 0, stream>>>(preds, gts, ws);
  reg_l1_final<<<B_, 64, 0, stream>>>(ws, out);
}